// Round 1
// baseline (860.857 us; speedup 1.0000x reference)
//
#include <hip/hip_runtime.h>
#include <math.h>

#define N_TOK 4096
#define C_DIM 256
#define HEADS 8
#define HDIM  32
#define SCALE 0.17677669529663687f

typedef float f32x4 __attribute__((ext_vector_type(4)));
typedef int   i32x4 __attribute__((ext_vector_type(4)));

__device__ __forceinline__ unsigned short f2bf(float x){
  unsigned u = __float_as_uint(x);
  u += 0x7FFFu + ((u >> 16) & 1u);
  return (unsigned short)(u >> 16);
}

// D = A(16x32) * B(32x16) + C via v_mfma_f32_16x16x32_bf16.
// A-frag: lane holds A[l&15][(l>>4)*8 + j] (8 contiguous bf16)
// B-frag: lane holds B[(l>>4)*8 + j][l&15]  (= row-major [col][k] source, 8 contiguous)
// D:      lane,reg r -> D[(l>>4)*4 + r][l&15]   (verified layout)
__device__ __forceinline__ f32x4 mfma16(i32x4 a, i32x4 b, f32x4 c){
  f32x4 d;
  asm volatile("v_mfma_f32_16x16x32_bf16 %0, %1, %2, %3\n\ts_nop 7\n\ts_nop 3"
               : "=&v"(d) : "v"(a), "v"(b), "v"(c));
  return d;
}

// ---------------- LayerNorm (one row of 256 per block) ----------------
template<int TO_BF>
__global__ __launch_bounds__(256) void ln_kernel(const float* __restrict__ x,
    const float* __restrict__ g, const float* __restrict__ b,
    float* __restrict__ outF, unsigned short* __restrict__ outB)
{
  int row = blockIdx.x, c = threadIdx.x;
  float v = x[(size_t)row*C_DIM + c];
  float s1 = v, s2 = v*v;
  #pragma unroll
  for (int off=1; off<64; off<<=1){
    s1 += __shfl_xor(s1, off);
    s2 += __shfl_xor(s2, off);
  }
  __shared__ float r1[4], r2[4];
  int wv = c >> 6;
  if ((c & 63) == 0){ r1[wv] = s1; r2[wv] = s2; }
  __syncthreads();
  s1 = r1[0]+r1[1]+r1[2]+r1[3];
  s2 = r2[0]+r2[1]+r2[2]+r2[3];
  float mu  = s1 * (1.0f/C_DIM);
  float var = s2 * (1.0f/C_DIM) - mu*mu;
  float inv = 1.0f / sqrtf(var + 1e-5f);
  float o = (v - mu) * inv * g[c] + b[c];
  if (TO_BF) outB[(size_t)row*C_DIM + c] = f2bf(o);
  else       outF[(size_t)row*C_DIM + c] = o;
}

// ---------------- 64x64 tiled transpose: src[R][C] -> dst[C][R] ----------------
__global__ __launch_bounds__(256) void transpose_k(const float* __restrict__ src,
    float* __restrict__ dstF, unsigned short* __restrict__ dstB, int R, int Cc)
{
  __shared__ float t[64][65];
  int c0 = blockIdx.x*64, r0 = blockIdx.y*64;
  int x = threadIdx.x & 63, ys = threadIdx.x >> 6;
  #pragma unroll
  for (int i=0;i<16;++i){
    int r = ys + i*4;
    t[r][x] = src[(size_t)(r0+r)*Cc + c0 + x];
  }
  __syncthreads();
  #pragma unroll
  for (int i=0;i<16;++i){
    int rr = ys + i*4;
    float val = t[x][rr];
    if (dstB) dstB[(size_t)(c0+rr)*R + r0 + x] = f2bf(val);
    else      dstF[(size_t)(c0+rr)*R + r0 + x] = val;
  }
}

__global__ void cvt_bf(const float* __restrict__ src, unsigned short* __restrict__ dst, int n){
  int i = blockIdx.x*256 + threadIdx.x;
  if (i < n) dst[i] = f2bf(src[i]);
}

// ---------------- bf16 MFMA GEMM: out[M][256] = A[M][K] @ Wt[N][K]^T (+bias, relu, resid) ----
// grid (M/32, 256/64), block 128 (2 waves, 16 rows each)
template<int RELU>
__global__ __launch_bounds__(128) void gemm_mfma(
    const unsigned short* __restrict__ A, const unsigned short* __restrict__ Wt,
    const float* __restrict__ bias, const float* __restrict__ resid,
    float* __restrict__ outF, unsigned short* __restrict__ outB, int K)
{
  int wave = threadIdx.x >> 6, lane = threadIdx.x & 63;
  int l16 = lane & 15, lg = lane >> 4;
  int m0 = blockIdx.x*32 + wave*16;
  int n0 = blockIdx.y*64;
  f32x4 acc0={0.f,0.f,0.f,0.f}, acc1=acc0, acc2=acc0, acc3=acc0;
  const unsigned short* ap  = A  + (size_t)(m0+l16)*K + lg*8;
  const unsigned short* bp0 = Wt + (size_t)(n0+ 0+l16)*K + lg*8;
  const unsigned short* bp1 = Wt + (size_t)(n0+16+l16)*K + lg*8;
  const unsigned short* bp2 = Wt + (size_t)(n0+32+l16)*K + lg*8;
  const unsigned short* bp3 = Wt + (size_t)(n0+48+l16)*K + lg*8;
  for (int ks = 0; ks < K; ks += 32){
    i32x4 af = *(const i32x4*)(ap + ks);
    acc0 = mfma16(af, *(const i32x4*)(bp0 + ks), acc0);
    acc1 = mfma16(af, *(const i32x4*)(bp1 + ks), acc1);
    acc2 = mfma16(af, *(const i32x4*)(bp2 + ks), acc2);
    acc3 = mfma16(af, *(const i32x4*)(bp3 + ks), acc3);
  }
  #pragma unroll
  for (int f=0; f<4; ++f){
    f32x4 acc = (f==0)?acc0 : (f==1)?acc1 : (f==2)?acc2 : acc3;
    int n = n0 + f*16 + l16;
    float bb = bias[n];
    #pragma unroll
    for (int r=0;r<4;++r){
      int m = m0 + lg*4 + r;
      float val = acc[r] + bb;
      if (RELU) val = fmaxf(val, 0.0f);
      if (resid) val += resid[(size_t)m*C_DIM + n];
      if (outF) outF[(size_t)m*C_DIM + n] = val;
      if (outB) outB[(size_t)m*C_DIM + n] = f2bf(val);
    }
  }
}

// ---------------- column sum of v (for closed-form softmax) ----------------
__global__ __launch_bounds__(256) void colsum_part(const float* __restrict__ v, float* __restrict__ part){
  int b = blockIdx.x, c = threadIdx.x;
  float s = 0.f;
  for (int r=0;r<64;++r) s += v[(size_t)(b*64+r)*C_DIM + c];
  part[b*C_DIM + c] = s;
}
__global__ __launch_bounds__(256) void colsum_final(const float* __restrict__ part, float* __restrict__ sumv){
  int c = threadIdx.x;
  float s = 0.f;
  for (int b=0;b<64;++b) s += part[b*C_DIM + c];
  sumv[c] = s;
}

// ---------------- fused scores + top-8 + closed-form softmax + PV ----------------
#define CMPEX(i,j) { bool sw = (tv[j] > tv[i]) || (tv[j]==tv[i] && ti[j]<ti[i]); \
  float fv_ = sw?tv[j]:tv[i]; float sv_ = sw?tv[i]:tv[j]; \
  int fi_ = sw?ti[j]:ti[i]; int si_ = sw?ti[i]:ti[j]; \
  tv[i]=fv_; tv[j]=sv_; ti[i]=fi_; ti[j]=si_; }

__global__ __launch_bounds__(256) void attn_kernel(
    const unsigned short* __restrict__ qbf, const unsigned short* __restrict__ kbf,
    const float* __restrict__ v, const float* __restrict__ sumv,
    unsigned short* __restrict__ outbf)
{
  int head = blockIdx.y;
  int wave = threadIdx.x >> 6, lane = threadIdx.x & 63;
  int l16 = lane & 15, lg = lane >> 4;
  int row0 = blockIdx.x*64 + wave*16;
  // B-frag: q-rows of this wave (col = q-row local = l16)
  i32x4 qfrag = *(const i32x4*)(qbf + (size_t)(row0+l16)*C_DIM + head*HDIM + lg*8);
  float tv[8]; int ti[8];
  #pragma unroll
  for (int j=0;j<8;++j){ tv[j] = -3e38f; ti[j] = 0; }
  for (int t=0; t<256; ++t){
    // A-frag: 16 k-rows of this tile
    i32x4 kfrag = *(const i32x4*)(kbf + (size_t)(t*16+l16)*C_DIM + head*HDIM + lg*8);
    f32x4 acc = {0.f,0.f,0.f,0.f};
    acc = mfma16(kfrag, qfrag, acc);
    // lane's q-row = row0+l16 ; candidate k-cols = t*16 + lg*4 + r
    int colb = t*16 + lg*4;
    #pragma unroll
    for (int r=0;r<4;++r){
      float s = acc[r];
      if (s > tv[7]){
        float cv = s; int ci = colb + r;
        #pragma unroll
        for (int j=0;j<8;++j){
          bool gt = cv > tv[j];
          float nv = gt?cv:tv[j]; float ov_ = gt?tv[j]:cv;
          int   ni = gt?ci:ti[j]; int   oi_ = gt?ti[j]:ci;
          tv[j]=nv; ti[j]=ni; cv=ov_; ci=oi_;
        }
      }
    }
  }
  // merge the 4 lane-groups holding the same q-row (bitonic top-8 of two sorted 8-lists)
  #pragma unroll
  for (int m=16; m<=32; m<<=1){
    float ov[8]; int oi[8];
    #pragma unroll
    for (int j=0;j<8;++j){ ov[j] = __shfl_xor(tv[j], m); oi[j] = __shfl_xor(ti[j], m); }
    #pragma unroll
    for (int j=0;j<8;++j){
      float bv = ov[7-j]; int bi = oi[7-j];
      bool take = (bv > tv[j]) || (bv == tv[j] && bi < ti[j]);
      tv[j] = take?bv:tv[j]; ti[j] = take?bi:ti[j];
    }
    CMPEX(0,4) CMPEX(1,5) CMPEX(2,6) CMPEX(3,7)
    CMPEX(0,2) CMPEX(1,3) CMPEX(4,6) CMPEX(5,7)
    CMPEX(0,1) CMPEX(2,3) CMPEX(4,5) CMPEX(6,7)
  }
  __shared__ float lds_e[4][16][8];
  __shared__ int   lds_i[4][16][8];
  __shared__ float lds_d[4][16];
  if (lg == 0){
    float den = 4096.0f;
    #pragma unroll
    for (int j=0;j<8;++j){
      float e = expm1f(tv[j]*SCALE);
      den += e;
      lds_e[wave][l16][j] = e;
      lds_i[wave][l16][j] = ti[j];
    }
    lds_d[wave][l16] = den;
  }
  __syncthreads();
  // out[row][head*32+d] = (sumv + sum_j e_j * v[idx_j]) / den
  #pragma unroll
  for (int it=0; it<8; ++it){
    int flat = it*256 + threadIdx.x;      // 64 rows x 32 dims
    int rloc = flat >> 5, d = flat & 31;
    int w2 = rloc >> 4, r2 = rloc & 15;
    float num = sumv[head*HDIM + d];
    float den = lds_d[w2][r2];
    #pragma unroll
    for (int j=0;j<8;++j)
      num += lds_e[w2][r2][j] * v[(size_t)lds_i[w2][r2][j]*C_DIM + head*HDIM + d];
    int row = blockIdx.x*64 + rloc;
    outbf[(size_t)row*C_DIM + head*HDIM + d] = f2bf(num/den);
  }
}

// ---------------- grouped dwconv 3x3 & 5x5 -> cat[p][2048] bf16 ----------------
__global__ __launch_bounds__(256) void dwconv_kernel(const float* __restrict__ img, // h2T [256][4096]
    const float* __restrict__ w3, const float* __restrict__ b3,
    const float* __restrict__ w5, const float* __restrict__ b5,
    unsigned short* __restrict__ cat)
{
  int flat = blockIdx.x*256 + threadIdx.x;   // o fastest -> coalesced [p][o] writes
  int o = flat & 2047;
  int p = flat >> 11;
  int py = p >> 6, px = p & 63;
  float acc;
  if (o < 1024) {
    int ic = o >> 2; acc = b3[o];
    const float* wp = w3 + o*9;
    const float* base = img + (size_t)ic*4096;
    #pragma unroll
    for (int dy=-1; dy<=1; ++dy)
      #pragma unroll
      for (int dx=-1; dx<=1; ++dx) {
        int yy = py+dy, xx = px+dx;
        float iv = (yy>=0 && yy<64 && xx>=0 && xx<64) ? base[yy*64+xx] : 0.f;
        acc += wp[(dy+1)*3 + (dx+1)] * iv;
      }
  } else {
    int o5 = o - 1024; int ic = o5 >> 2; acc = b5[o5];
    const float* wp = w5 + o5*25;
    const float* base = img + (size_t)ic*4096;
    #pragma unroll
    for (int dy=-2; dy<=2; ++dy)
      #pragma unroll
      for (int dx=-2; dx<=2; ++dx) {
        int yy = py+dy, xx = px+dx;
        float iv = (yy>=0 && yy<64 && xx>=0 && xx<64) ? base[yy*64+xx] : 0.f;
        acc += wp[(dy+2)*5 + (dx+2)] * iv;
      }
  }
  cat[(size_t)p*2048 + o] = f2bf(fmaxf(acc, 0.f));
}

extern "C" void kernel_launch(void* const* d_in, const int* in_sizes, int n_in,
                              void* d_out, int out_size, void* d_ws, size_t ws_size,
                              hipStream_t stream)
{
  (void)in_sizes; (void)n_in; (void)out_size; (void)ws_size;
  const float* x      = (const float*)d_in[0];
  const float* ln1_g  = (const float*)d_in[3];
  const float* ln1_b  = (const float*)d_in[4];
  const float* q_w    = (const float*)d_in[5];
  const float* q_b    = (const float*)d_in[6];
  const float* kv_w   = (const float*)d_in[7];
  const float* kv_b   = (const float*)d_in[8];
  const float* proj_w = (const float*)d_in[9];
  const float* proj_b = (const float*)d_in[10];
  const float* ln2_g  = (const float*)d_in[11];
  const float* ln2_b  = (const float*)d_in[12];
  const float* w3     = (const float*)d_in[13];
  const float* b3     = (const float*)d_in[14];
  const float* w5     = (const float*)d_in[15];
  const float* b5     = (const float*)d_in[16];
  const float* w1     = (const float*)d_in[17];
  const float* b1     = (const float*)d_in[18];
  float* out = (float*)d_out;
  char* ws = (char*)d_ws;

  unsigned short* qwT  = (unsigned short*)(ws + 0x0);       // 128 KB
  unsigned short* pwT  = (unsigned short*)(ws + 0x20000);   // 128 KB
  unsigned short* kvwT = (unsigned short*)(ws + 0x40000);   // 256 KB
  unsigned short* w1bf = (unsigned short*)(ws + 0x80000);   // 1 MB
  unsigned short* hbf  = (unsigned short*)(ws + 0x180000);  // 2 MB
  unsigned short* qbf  = (unsigned short*)(ws + 0x380000);  // 2 MB
  unsigned short* kbf  = (unsigned short*)(ws + 0x580000);  // 2 MB
  float*          vbuf = (float*)(ws + 0x780000);           // 4 MB
  unsigned short* obf  = (unsigned short*)(ws + 0xB80000);  // 2 MB
  float*          x2   = (float*)(ws + 0xD80000);           // 4 MB
  float*          sumv = (float*)(ws + 0x1180000);          // 1 KB
  float*          part = (float*)(ws + 0x1190000);          // 64 KB
  float*          h2   = (float*)(ws + 0x180000);           // reuse hbf+qbf (dead)
  float*          h2T  = (float*)(ws + 0x580000);           // reuse kbf+v half (dead)
  unsigned short* cat  = (unsigned short*)(ws + 0x1200000); // 16 MB -> end 0x2200000

  dim3 b256(256), b128(128);

  // weight prep
  cvt_bf<<<dim3(2048), b256, 0, stream>>>(w1, w1bf, 256*2048);
  transpose_k<<<dim3(4,4), b256, 0, stream>>>(q_w,   nullptr, qwT,  256, 256);
  transpose_k<<<dim3(8,4), b256, 0, stream>>>(kv_w,  nullptr, kvwT, 256, 512);
  transpose_k<<<dim3(4,4), b256, 0, stream>>>(proj_w,nullptr, pwT,  256, 256);

  // attention branch
  ln_kernel<1><<<dim3(4096), b256, 0, stream>>>(x, ln1_g, ln1_b, nullptr, hbf);
  gemm_mfma<1><<<dim3(128,4), b128, 0, stream>>>(hbf, qwT,           q_b,      nullptr, nullptr, qbf, 256);
  gemm_mfma<0><<<dim3(128,4), b128, 0, stream>>>(hbf, kvwT,          kv_b,     nullptr, nullptr, kbf, 256);
  gemm_mfma<0><<<dim3(128,4), b128, 0, stream>>>(hbf, kvwT + 256*256, kv_b+256, nullptr, vbuf,   nullptr, 256);
  colsum_part <<<dim3(64), b256, 0, stream>>>(vbuf, part);
  colsum_final<<<dim3(1),  b256, 0, stream>>>(part, sumv);
  attn_kernel<<<dim3(64,8), b256, 0, stream>>>(qbf, kbf, vbuf, sumv, obf);
  gemm_mfma<0><<<dim3(128,4), b128, 0, stream>>>(obf, pwT, proj_b, x, x2, nullptr, 256);

  // MSFN branch
  ln_kernel<0><<<dim3(4096), b256, 0, stream>>>(x2, ln2_g, ln2_b, h2, nullptr);
  transpose_k<<<dim3(4,64), b256, 0, stream>>>(h2, h2T, nullptr, 4096, 256);
  dwconv_kernel<<<dim3(32768), b256, 0, stream>>>(h2T, w3, b3, w5, b5, cat);
  gemm_mfma<0><<<dim3(128,4), b128, 0, stream>>>(cat, w1bf, b1, x2, out, nullptr, 2048);
}

// Round 2
// 347.513 us; speedup vs baseline: 2.4772x; 2.4772x over previous
//
#include <hip/hip_runtime.h>
#include <math.h>

#define N_TOK 4096
#define C_DIM 256
#define HEADS 8
#define HDIM  32
#define SCALE 0.17677669529663687f

typedef float f32x4 __attribute__((ext_vector_type(4)));
typedef int   i32x4 __attribute__((ext_vector_type(4)));

__device__ __forceinline__ unsigned short f2bf(float x){
  unsigned u = __float_as_uint(x);
  u += 0x7FFFu + ((u >> 16) & 1u);
  return (unsigned short)(u >> 16);
}

// D = A(16x32) * B(32x16) + C via v_mfma_f32_16x16x32_bf16.
// A-frag: lane holds A[l&15][(l>>4)*8 + j] (8 contiguous bf16)
// B-frag: lane holds B[(l>>4)*8 + j][l&15]  (= row-major [col][k] source, 8 contiguous)
// D:      lane,reg r -> D[(l>>4)*4 + r][l&15]   (verified layout)
__device__ __forceinline__ f32x4 mfma16(i32x4 a, i32x4 b, f32x4 c){
  f32x4 d;
  asm volatile("v_mfma_f32_16x16x32_bf16 %0, %1, %2, %3\n\ts_nop 7\n\ts_nop 3"
               : "=&v"(d) : "v"(a), "v"(b), "v"(c));
  return d;
}

// ---------------- LayerNorm (one row of 256 per block) ----------------
template<int TO_BF>
__global__ __launch_bounds__(256) void ln_kernel(const float* __restrict__ x,
    const float* __restrict__ g, const float* __restrict__ b,
    float* __restrict__ outF, unsigned short* __restrict__ outB)
{
  int row = blockIdx.x, c = threadIdx.x;
  float v = x[(size_t)row*C_DIM + c];
  float s1 = v, s2 = v*v;
  #pragma unroll
  for (int off=1; off<64; off<<=1){
    s1 += __shfl_xor(s1, off);
    s2 += __shfl_xor(s2, off);
  }
  __shared__ float r1[4], r2[4];
  int wv = c >> 6;
  if ((c & 63) == 0){ r1[wv] = s1; r2[wv] = s2; }
  __syncthreads();
  s1 = r1[0]+r1[1]+r1[2]+r1[3];
  s2 = r2[0]+r2[1]+r2[2]+r2[3];
  float mu  = s1 * (1.0f/C_DIM);
  float var = s2 * (1.0f/C_DIM) - mu*mu;
  float inv = 1.0f / sqrtf(var + 1e-5f);
  float o = (v - mu) * inv * g[c] + b[c];
  if (TO_BF) outB[(size_t)row*C_DIM + c] = f2bf(o);
  else       outF[(size_t)row*C_DIM + c] = o;
}

// ---------------- 64x64 tiled transpose: src[R][C] -> dst[C][R] ----------------
__global__ __launch_bounds__(256) void transpose_k(const float* __restrict__ src,
    float* __restrict__ dstF, unsigned short* __restrict__ dstB, int R, int Cc)
{
  __shared__ float t[64][65];
  int c0 = blockIdx.x*64, r0 = blockIdx.y*64;
  int x = threadIdx.x & 63, ys = threadIdx.x >> 6;
  #pragma unroll
  for (int i=0;i<16;++i){
    int r = ys + i*4;
    t[r][x] = src[(size_t)(r0+r)*Cc + c0 + x];
  }
  __syncthreads();
  #pragma unroll
  for (int i=0;i<16;++i){
    int rr = ys + i*4;
    float val = t[x][rr];
    if (dstB) dstB[(size_t)(c0+rr)*R + r0 + x] = f2bf(val);
    else      dstF[(size_t)(c0+rr)*R + r0 + x] = val;
  }
}

__global__ void cvt_bf(const float* __restrict__ src, unsigned short* __restrict__ dst, int n){
  int i = blockIdx.x*256 + threadIdx.x;
  if (i < n) dst[i] = f2bf(src[i]);
}

// ---------------- bf16 MFMA GEMM: out[M][256] = A[M][K] @ Wt[N][K]^T (+bias, relu, resid) ----
// grid (M/32, 256/64), block 128 (2 waves, 16 rows each)
template<int RELU>
__global__ __launch_bounds__(128) void gemm_mfma(
    const unsigned short* __restrict__ A, const unsigned short* __restrict__ Wt,
    const float* __restrict__ bias, const float* __restrict__ resid,
    float* __restrict__ outF, unsigned short* __restrict__ outB, int K)
{
  int wave = threadIdx.x >> 6, lane = threadIdx.x & 63;
  int l16 = lane & 15, lg = lane >> 4;
  int m0 = blockIdx.x*32 + wave*16;
  int n0 = blockIdx.y*64;
  f32x4 acc0={0.f,0.f,0.f,0.f}, acc1=acc0, acc2=acc0, acc3=acc0;
  const unsigned short* ap  = A  + (size_t)(m0+l16)*K + lg*8;
  const unsigned short* bp0 = Wt + (size_t)(n0+ 0+l16)*K + lg*8;
  const unsigned short* bp1 = Wt + (size_t)(n0+16+l16)*K + lg*8;
  const unsigned short* bp2 = Wt + (size_t)(n0+32+l16)*K + lg*8;
  const unsigned short* bp3 = Wt + (size_t)(n0+48+l16)*K + lg*8;
  for (int ks = 0; ks < K; ks += 32){
    i32x4 af = *(const i32x4*)(ap + ks);
    acc0 = mfma16(af, *(const i32x4*)(bp0 + ks), acc0);
    acc1 = mfma16(af, *(const i32x4*)(bp1 + ks), acc1);
    acc2 = mfma16(af, *(const i32x4*)(bp2 + ks), acc2);
    acc3 = mfma16(af, *(const i32x4*)(bp3 + ks), acc3);
  }
  #pragma unroll
  for (int f=0; f<4; ++f){
    f32x4 acc = (f==0)?acc0 : (f==1)?acc1 : (f==2)?acc2 : acc3;
    int n = n0 + f*16 + l16;
    float bb = bias[n];
    #pragma unroll
    for (int r=0;r<4;++r){
      int m = m0 + lg*4 + r;
      float val = acc[r] + bb;
      if (RELU) val = fmaxf(val, 0.0f);
      if (resid) val += resid[(size_t)m*C_DIM + n];
      if (outF) outF[(size_t)m*C_DIM + n] = val;
      if (outB) outB[(size_t)m*C_DIM + n] = f2bf(val);
    }
  }
}

// ---------------- column sum of v (for closed-form softmax) ----------------
__global__ __launch_bounds__(256) void colsum_part(const float* __restrict__ v, float* __restrict__ part){
  int b = blockIdx.x, c = threadIdx.x;
  float s = 0.f;
  for (int r=0;r<64;++r) s += v[(size_t)(b*64+r)*C_DIM + c];
  part[b*C_DIM + c] = s;
}
__global__ __launch_bounds__(256) void colsum_final(const float* __restrict__ part, float* __restrict__ sumv){
  int c = threadIdx.x;
  float s = 0.f;
  for (int b=0;b<64;++b) s += part[b*C_DIM + c];
  sumv[c] = s;
}

// ---------------- fused scores + top-8 + closed-form softmax + PV ----------------
#define CMPEX(i,j) { bool sw = (tv[j] > tv[i]) || (tv[j]==tv[i] && ti[j]<ti[i]); \
  float fv_ = sw?tv[j]:tv[i]; float sv_ = sw?tv[i]:tv[j]; \
  int fi_ = sw?ti[j]:ti[i]; int si_ = sw?ti[i]:ti[j]; \
  tv[i]=fv_; tv[j]=sv_; ti[i]=fi_; ti[j]=si_; }

__global__ __launch_bounds__(256) void attn_kernel(
    const unsigned short* __restrict__ qbf, const unsigned short* __restrict__ kbf,
    const float* __restrict__ v, const float* __restrict__ sumv,
    unsigned short* __restrict__ outbf)
{
  int head = blockIdx.y;
  int wave = threadIdx.x >> 6, lane = threadIdx.x & 63;
  int l16 = lane & 15, lg = lane >> 4;
  int row0 = blockIdx.x*64 + wave*16;
  // B-frag: q-rows of this wave (col = q-row local = l16)
  i32x4 qfrag = *(const i32x4*)(qbf + (size_t)(row0+l16)*C_DIM + head*HDIM + lg*8);
  float tv[8]; int ti[8];
  #pragma unroll
  for (int j=0;j<8;++j){ tv[j] = -3e38f; ti[j] = 0; }
  for (int t=0; t<256; ++t){
    // A-frag: 16 k-rows of this tile
    i32x4 kfrag = *(const i32x4*)(kbf + (size_t)(t*16+l16)*C_DIM + head*HDIM + lg*8);
    f32x4 acc = {0.f,0.f,0.f,0.f};
    acc = mfma16(kfrag, qfrag, acc);
    // lane's q-row = row0+l16 ; candidate k-cols = t*16 + lg*4 + r
    int colb = t*16 + lg*4;
    #pragma unroll
    for (int r=0;r<4;++r){
      float s = acc[r];
      if (s > tv[7]){
        float cv = s; int ci = colb + r;
        #pragma unroll
        for (int j=0;j<8;++j){
          bool gt = cv > tv[j];
          float nv = gt?cv:tv[j]; float ov_ = gt?tv[j]:cv;
          int   ni = gt?ci:ti[j]; int   oi_ = gt?ti[j]:ci;
          tv[j]=nv; ti[j]=ni; cv=ov_; ci=oi_;
        }
      }
    }
  }
  // merge the 4 lane-groups holding the same q-row (bitonic top-8 of two sorted 8-lists)
  #pragma unroll
  for (int m=16; m<=32; m<<=1){
    float ov[8]; int oi[8];
    #pragma unroll
    for (int j=0;j<8;++j){ ov[j] = __shfl_xor(tv[j], m); oi[j] = __shfl_xor(ti[j], m); }
    #pragma unroll
    for (int j=0;j<8;++j){
      float bv = ov[7-j]; int bi = oi[7-j];
      bool take = (bv > tv[j]) || (bv == tv[j] && bi < ti[j]);
      tv[j] = take?bv:tv[j]; ti[j] = take?bi:ti[j];
    }
    CMPEX(0,4) CMPEX(1,5) CMPEX(2,6) CMPEX(3,7)
    CMPEX(0,2) CMPEX(1,3) CMPEX(4,6) CMPEX(5,7)
    CMPEX(0,1) CMPEX(2,3) CMPEX(4,5) CMPEX(6,7)
  }
  __shared__ float lds_e[4][16][8];
  __shared__ int   lds_i[4][16][8];
  __shared__ float lds_d[4][16];
  if (lg == 0){
    float den = 4096.0f;
    #pragma unroll
    for (int j=0;j<8;++j){
      float e = expm1f(tv[j]*SCALE);
      den += e;
      lds_e[wave][l16][j] = e;
      lds_i[wave][l16][j] = ti[j];
    }
    lds_d[wave][l16] = den;
  }
  __syncthreads();
  // out[row][head*32+d] = (sumv + sum_j e_j * v[idx_j]) / den
  #pragma unroll
  for (int it=0; it<8; ++it){
    int flat = it*256 + threadIdx.x;      // 64 rows x 32 dims
    int rloc = flat >> 5, d = flat & 31;
    int w2 = rloc >> 4, r2 = rloc & 15;
    float num = sumv[head*HDIM + d];
    float den = lds_d[w2][r2];
    #pragma unroll
    for (int j=0;j<8;++j)
      num += lds_e[w2][r2][j] * v[(size_t)lds_i[w2][r2][j]*C_DIM + head*HDIM + d];
    int row = blockIdx.x*64 + rloc;
    outbf[(size_t)row*C_DIM + head*HDIM + d] = f2bf(num/den);
  }
}

// ---------------- LDS-tiled grouped dwconv 3x3 & 5x5 -> cat[p][2048] bf16 ----------------
// block: 8 input channels x 4-row pixel stripe (+-2 halo). 256 threads = 32 o_local x 8 p.
__global__ __launch_bounds__(256) void dwconv_tiled(const float* __restrict__ img, // h2T [256][4096]
    const float* __restrict__ w3, const float* __restrict__ b3,
    const float* __restrict__ w5, const float* __restrict__ b5,
    unsigned short* __restrict__ cat)
{
  __shared__ float tile[8][513];         // 8 channel planes of 8x64, stride 513 (bank spread)
  int ic0 = blockIdx.x * 8;              // input channel group
  int py0 = blockIdx.y * 4;              // pixel row stripe
  int tid = threadIdx.x;

  // stage: 8 ch x 8 rows (py0-2 .. py0+5) x 64, coalesced 256B row segments
  #pragma unroll
  for (int i = 0; i < 16; ++i){
    int idx = i*256 + tid;
    int ch  = idx >> 9;
    int rem = idx & 511;
    int ry  = rem >> 6, x = rem & 63;
    int y   = py0 - 2 + ry;
    float v = (y >= 0 && y < 64) ? img[(size_t)(ic0+ch)*4096 + y*64 + x] : 0.f;
    tile[ch][ry*64 + x] = v;
  }
  __syncthreads();

  int o_l  = tid & 31;                   // 0..31 : ic_l = o_l>>2, multiplier j = o_l&3
  int p_l  = tid >> 5;                   // 0..7
  int ic_l = o_l >> 2;
  int o3   = ic0*4 + o_l;                // output channel index (same for w3/b3 and w5/b5)
  const float* pl = tile[ic_l];

  float W3[9], W5[25];
  #pragma unroll
  for (int i=0;i<9;++i)  W3[i] = w3[o3*9+i];
  #pragma unroll
  for (int i=0;i<25;++i) W5[i] = w5[o3*25+i];
  float bb3 = b3[o3], bb5 = b5[o3];

  #pragma unroll 4
  for (int it = 0; it < 32; ++it){
    int pp = it*8 + p_l;                 // local pixel 0..255
    int ly = (pp >> 6) + 2;              // local row in tile
    int x  = pp & 63;
    float a3 = bb3, a5 = bb5;
    #pragma unroll
    for (int dy=-2; dy<=2; ++dy){
      #pragma unroll
      for (int dx=-2; dx<=2; ++dx){
        int xx = x + dx;
        float iv = (xx >= 0 && xx < 64) ? pl[(ly+dy)*64 + xx] : 0.f;
        a5 += W5[(dy+2)*5 + dx+2] * iv;
        if (dy>=-1 && dy<=1 && dx>=-1 && dx<=1)
          a3 += W3[(dy+1)*3 + dx+1] * iv;
      }
    }
    int p = (py0 + (pp>>6))*64 + x;      // global pixel
    cat[(size_t)p*2048 + o3]        = f2bf(fmaxf(a3, 0.f));
    cat[(size_t)p*2048 + 1024 + o3] = f2bf(fmaxf(a5, 0.f));
  }
}

extern "C" void kernel_launch(void* const* d_in, const int* in_sizes, int n_in,
                              void* d_out, int out_size, void* d_ws, size_t ws_size,
                              hipStream_t stream)
{
  (void)in_sizes; (void)n_in; (void)out_size; (void)ws_size;
  const float* x      = (const float*)d_in[0];
  const float* ln1_g  = (const float*)d_in[3];
  const float* ln1_b  = (const float*)d_in[4];
  const float* q_w    = (const float*)d_in[5];
  const float* q_b    = (const float*)d_in[6];
  const float* kv_w   = (const float*)d_in[7];
  const float* kv_b   = (const float*)d_in[8];
  const float* proj_w = (const float*)d_in[9];
  const float* proj_b = (const float*)d_in[10];
  const float* ln2_g  = (const float*)d_in[11];
  const float* ln2_b  = (const float*)d_in[12];
  const float* w3     = (const float*)d_in[13];
  const float* b3     = (const float*)d_in[14];
  const float* w5     = (const float*)d_in[15];
  const float* b5     = (const float*)d_in[16];
  const float* w1     = (const float*)d_in[17];
  const float* b1     = (const float*)d_in[18];
  float* out = (float*)d_out;
  char* ws = (char*)d_ws;

  unsigned short* qwT  = (unsigned short*)(ws + 0x0);       // 128 KB
  unsigned short* pwT  = (unsigned short*)(ws + 0x20000);   // 128 KB
  unsigned short* kvwT = (unsigned short*)(ws + 0x40000);   // 256 KB
  unsigned short* w1bf = (unsigned short*)(ws + 0x80000);   // 1 MB
  unsigned short* hbf  = (unsigned short*)(ws + 0x180000);  // 2 MB
  unsigned short* qbf  = (unsigned short*)(ws + 0x380000);  // 2 MB
  unsigned short* kbf  = (unsigned short*)(ws + 0x580000);  // 2 MB
  float*          vbuf = (float*)(ws + 0x780000);           // 4 MB
  unsigned short* obf  = (unsigned short*)(ws + 0xB80000);  // 2 MB
  float*          x2   = (float*)(ws + 0xD80000);           // 4 MB
  float*          sumv = (float*)(ws + 0x1180000);          // 1 KB
  float*          part = (float*)(ws + 0x1190000);          // 64 KB
  float*          h2   = (float*)(ws + 0x180000);           // reuse hbf+qbf (dead)
  float*          h2T  = (float*)(ws + 0x580000);           // reuse kbf+v half (dead)
  unsigned short* cat  = (unsigned short*)(ws + 0x1200000); // 16 MB -> end 0x2200000

  dim3 b256(256), b128(128);

  // weight prep
  cvt_bf<<<dim3(2048), b256, 0, stream>>>(w1, w1bf, 256*2048);
  transpose_k<<<dim3(4,4), b256, 0, stream>>>(q_w,   nullptr, qwT,  256, 256);
  transpose_k<<<dim3(8,4), b256, 0, stream>>>(kv_w,  nullptr, kvwT, 256, 512);
  transpose_k<<<dim3(4,4), b256, 0, stream>>>(proj_w,nullptr, pwT,  256, 256);

  // attention branch
  ln_kernel<1><<<dim3(4096), b256, 0, stream>>>(x, ln1_g, ln1_b, nullptr, hbf);
  gemm_mfma<1><<<dim3(128,4), b128, 0, stream>>>(hbf, qwT,           q_b,      nullptr, nullptr, qbf, 256);
  gemm_mfma<0><<<dim3(128,4), b128, 0, stream>>>(hbf, kvwT,          kv_b,     nullptr, nullptr, kbf, 256);
  gemm_mfma<0><<<dim3(128,4), b128, 0, stream>>>(hbf, kvwT + 256*256, kv_b+256, nullptr, vbuf,   nullptr, 256);
  colsum_part <<<dim3(64), b256, 0, stream>>>(vbuf, part);
  colsum_final<<<dim3(1),  b256, 0, stream>>>(part, sumv);
  attn_kernel<<<dim3(64,8), b256, 0, stream>>>(qbf, kbf, vbuf, sumv, obf);
  gemm_mfma<0><<<dim3(128,4), b128, 0, stream>>>(obf, pwT, proj_b, x, x2, nullptr, 256);

  // MSFN branch
  ln_kernel<0><<<dim3(4096), b256, 0, stream>>>(x2, ln2_g, ln2_b, h2, nullptr);
  transpose_k<<<dim3(4,64), b256, 0, stream>>>(h2, h2T, nullptr, 4096, 256);
  dwconv_tiled<<<dim3(32,16), b256, 0, stream>>>(h2T, w3, b3, w5, b5, cat);
  gemm_mfma<0><<<dim3(128,4), b128, 0, stream>>>(cat, w1bf, b1, x2, out, nullptr, 2048);
}

// Round 3
// 251.771 us; speedup vs baseline: 3.4192x; 1.3803x over previous
//
#include <hip/hip_runtime.h>
#include <math.h>

#define N_TOK 4096
#define C_DIM 256
#define HEADS 8
#define HDIM  32
#define SCALE 0.17677669529663687f

typedef float f32x4 __attribute__((ext_vector_type(4)));
typedef int   i32x4 __attribute__((ext_vector_type(4)));

__device__ __forceinline__ unsigned short f2bf(float x){
  unsigned u = __float_as_uint(x);
  u += 0x7FFFu + ((u >> 16) & 1u);
  return (unsigned short)(u >> 16);
}

// D = A(16x32) * B(32x16) + C via v_mfma_f32_16x16x32_bf16.
// A-frag: lane holds A[l&15][(l>>4)*8 + j] (8 contiguous bf16)
// B-frag: lane holds B[(l>>4)*8 + j][l&15]  (= row-major [col][k] source, 8 contiguous)
// D:      lane,reg r -> D[(l>>4)*4 + r][l&15]   (verified layout)
__device__ __forceinline__ f32x4 mfma16(i32x4 a, i32x4 b, f32x4 c){
  f32x4 d;
  asm volatile("v_mfma_f32_16x16x32_bf16 %0, %1, %2, %3\n\ts_nop 7\n\ts_nop 3"
               : "=&v"(d) : "v"(a), "v"(b), "v"(c));
  return d;
}

// ---------------- LayerNorm (one row of 256 per block) ----------------
template<int TO_BF>
__global__ __launch_bounds__(256) void ln_kernel(const float* __restrict__ x,
    const float* __restrict__ g, const float* __restrict__ b,
    float* __restrict__ outF, unsigned short* __restrict__ outB)
{
  int row = blockIdx.x, c = threadIdx.x;
  float v = x[(size_t)row*C_DIM + c];
  float s1 = v, s2 = v*v;
  #pragma unroll
  for (int off=1; off<64; off<<=1){
    s1 += __shfl_xor(s1, off);
    s2 += __shfl_xor(s2, off);
  }
  __shared__ float r1[4], r2[4];
  int wv = c >> 6;
  if ((c & 63) == 0){ r1[wv] = s1; r2[wv] = s2; }
  __syncthreads();
  s1 = r1[0]+r1[1]+r1[2]+r1[3];
  s2 = r2[0]+r2[1]+r2[2]+r2[3];
  float mu  = s1 * (1.0f/C_DIM);
  float var = s2 * (1.0f/C_DIM) - mu*mu;
  float inv = 1.0f / sqrtf(var + 1e-5f);
  float o = (v - mu) * inv * g[c] + b[c];
  if (TO_BF) outB[(size_t)row*C_DIM + c] = f2bf(o);
  else       outF[(size_t)row*C_DIM + c] = o;
}

// ---------------- 64x64 tiled transpose: src[R][C] -> dst[C][R] ----------------
__global__ __launch_bounds__(256) void transpose_k(const float* __restrict__ src,
    float* __restrict__ dstF, unsigned short* __restrict__ dstB, int R, int Cc)
{
  __shared__ float t[64][65];
  int c0 = blockIdx.x*64, r0 = blockIdx.y*64;
  int x = threadIdx.x & 63, ys = threadIdx.x >> 6;
  #pragma unroll
  for (int i=0;i<16;++i){
    int r = ys + i*4;
    t[r][x] = src[(size_t)(r0+r)*Cc + c0 + x];
  }
  __syncthreads();
  #pragma unroll
  for (int i=0;i<16;++i){
    int rr = ys + i*4;
    float val = t[x][rr];
    if (dstB) dstB[(size_t)(c0+rr)*R + r0 + x] = f2bf(val);
    else      dstF[(size_t)(c0+rr)*R + r0 + x] = val;
  }
}

__global__ void cvt_bf(const float* __restrict__ src, unsigned short* __restrict__ dst, int n){
  int i = blockIdx.x*256 + threadIdx.x;
  if (i < n) dst[i] = f2bf(src[i]);
}

// ---------------- bf16 MFMA GEMM: out[M][256] = A[M][K] @ Wt[N][K]^T (+bias, relu, resid) ----
// grid (M/32, 256/64), block 128 (2 waves, 16 rows each)
template<int RELU>
__global__ __launch_bounds__(128) void gemm_mfma(
    const unsigned short* __restrict__ A, const unsigned short* __restrict__ Wt,
    const float* __restrict__ bias, const float* __restrict__ resid,
    float* __restrict__ outF, unsigned short* __restrict__ outB, int K)
{
  int wave = threadIdx.x >> 6, lane = threadIdx.x & 63;
  int l16 = lane & 15, lg = lane >> 4;
  int m0 = blockIdx.x*32 + wave*16;
  int n0 = blockIdx.y*64;
  f32x4 acc0={0.f,0.f,0.f,0.f}, acc1=acc0, acc2=acc0, acc3=acc0;
  const unsigned short* ap  = A  + (size_t)(m0+l16)*K + lg*8;
  const unsigned short* bp0 = Wt + (size_t)(n0+ 0+l16)*K + lg*8;
  const unsigned short* bp1 = Wt + (size_t)(n0+16+l16)*K + lg*8;
  const unsigned short* bp2 = Wt + (size_t)(n0+32+l16)*K + lg*8;
  const unsigned short* bp3 = Wt + (size_t)(n0+48+l16)*K + lg*8;
  for (int ks = 0; ks < K; ks += 32){
    i32x4 af = *(const i32x4*)(ap + ks);
    acc0 = mfma16(af, *(const i32x4*)(bp0 + ks), acc0);
    acc1 = mfma16(af, *(const i32x4*)(bp1 + ks), acc1);
    acc2 = mfma16(af, *(const i32x4*)(bp2 + ks), acc2);
    acc3 = mfma16(af, *(const i32x4*)(bp3 + ks), acc3);
  }
  #pragma unroll
  for (int f=0; f<4; ++f){
    f32x4 acc = (f==0)?acc0 : (f==1)?acc1 : (f==2)?acc2 : acc3;
    int n = n0 + f*16 + l16;
    float bb = bias[n];
    #pragma unroll
    for (int r=0;r<4;++r){
      int m = m0 + lg*4 + r;
      float val = acc[r] + bb;
      if (RELU) val = fmaxf(val, 0.0f);
      if (resid) val += resid[(size_t)m*C_DIM + n];
      if (outF) outF[(size_t)m*C_DIM + n] = val;
      if (outB) outB[(size_t)m*C_DIM + n] = f2bf(val);
    }
  }
}

// ---------------- column sum of v (for closed-form softmax) ----------------
__global__ __launch_bounds__(256) void colsum_part(const float* __restrict__ v, float* __restrict__ part){
  int b = blockIdx.x, c = threadIdx.x;
  float s = 0.f;
  for (int r=0;r<64;++r) s += v[(size_t)(b*64+r)*C_DIM + c];
  part[b*C_DIM + c] = s;
}
__global__ __launch_bounds__(256) void colsum_final(const float* __restrict__ part, float* __restrict__ sumv){
  int c = threadIdx.x;
  float s = 0.f;
  for (int b=0;b<64;++b) s += part[b*C_DIM + c];
  sumv[c] = s;
}

// ---------------- fused scores + hierarchical exact top-8 + closed-form softmax + PV ----
// bitonic top-8 merge of two sorted lists across lane-groups (xor 16 then 32)
#define CMPEX(A,I,i,j) { bool sw = (A[j] > A[i]) || (A[j]==A[i] && I[j]<I[i]); \
  float fv_ = sw?A[j]:A[i]; float sv_ = sw?A[i]:A[j]; \
  int fi_ = sw?I[j]:I[i]; int si_ = sw?I[i]:I[j]; \
  A[i]=fv_; A[j]=sv_; I[i]=fi_; I[j]=si_; }

__device__ __forceinline__ void merge_lists(float (&tv)[8], int (&ti)[8]){
  #pragma unroll
  for (int m=16; m<=32; m<<=1){
    float ov[8]; int oi[8];
    #pragma unroll
    for (int j=0;j<8;++j){ ov[j] = __shfl_xor(tv[j], m); oi[j] = __shfl_xor(ti[j], m); }
    #pragma unroll
    for (int j=0;j<8;++j){
      float bv = ov[7-j]; int bi = oi[7-j];
      bool take = (bv > tv[j]) || (bv == tv[j] && bi < ti[j]);
      tv[j] = take?bv:tv[j]; ti[j] = take?bi:ti[j];
    }
    CMPEX(tv,ti,0,4) CMPEX(tv,ti,1,5) CMPEX(tv,ti,2,6) CMPEX(tv,ti,3,7)
    CMPEX(tv,ti,0,2) CMPEX(tv,ti,1,3) CMPEX(tv,ti,4,6) CMPEX(tv,ti,5,7)
    CMPEX(tv,ti,0,1) CMPEX(tv,ti,2,3) CMPEX(tv,ti,4,5) CMPEX(tv,ti,6,7)
  }
}

__global__ __launch_bounds__(256) void attn_kernel(
    const unsigned short* __restrict__ qbf, const unsigned short* __restrict__ kbf,
    const float* __restrict__ v, const float* __restrict__ sumv,
    unsigned short* __restrict__ outbf)
{
  int head = blockIdx.y;
  int wave = threadIdx.x >> 6, lane = threadIdx.x & 63;
  int l16 = lane & 15, lg = lane >> 4;
  int row0 = blockIdx.x*64 + wave*16;
  int row  = row0 + l16;
  // B-frag: q-rows of this wave (col = q-row local = l16)
  i32x4 qfrag = *(const i32x4*)(qbf + (size_t)row*C_DIM + head*HDIM + lg*8);
  const f32x4 zacc = {0.f,0.f,0.f,0.f};

  // ---- phase 1: per-lane top-8 of 256 subtile-maxes (subtile = this lane's 4 cols) ----
  float tv[8]; int ti[8];
  #pragma unroll
  for (int j=0;j<8;++j){ tv[j] = -3e38f; ti[j] = 0; }
  const unsigned short* kptr = kbf + (size_t)l16*C_DIM + head*HDIM + lg*8;
  i32x4 kf = *(const i32x4*)kptr;
  for (int t=0; t<256; ++t){
    i32x4 kn = *(const i32x4*)(kptr + (size_t)(t+1)*16*C_DIM);  // prefetch (last over-read lands in vbuf: safe)
    f32x4 acc = mfma16(kf, qfrag, zacc);
    kf = kn;
    float m = fmaxf(fmaxf(acc[0],acc[1]), fmaxf(acc[2],acc[3]));
    if (m > tv[7]){
      float cv = m; int ci = t*16 + lg*4;   // base column of this subtile
      #pragma unroll
      for (int j=0;j<8;++j){
        bool gt = cv > tv[j];               // strict: ascending-idx stream keeps earliest on tie
        float nv = gt?cv:tv[j]; float ov_ = gt?tv[j]:cv;
        int   ni = gt?ci:ti[j]; int   oi_ = gt?ti[j]:ci;
        tv[j]=nv; ti[j]=ni; cv=ov_; ci=oi_;
      }
    }
  }
  // top-8 subtiles per row (all 4 lane-groups end with identical sorted lists)
  merge_lists(tv, ti);

  // ---- phase 2: rescan the 8 selected subtiles (32 candidate cols) exactly ----
  float qf[32];
  {
    const unsigned short* qrow = qbf + (size_t)row*C_DIM + head*HDIM;
    #pragma unroll
    for (int i=0;i<4;++i){
      i32x4 qv = *(const i32x4*)(qrow + i*8);
      #pragma unroll
      for (int j=0;j<4;++j){
        unsigned u = (unsigned)qv[j];
        qf[i*8 + 2*j]   = __uint_as_float(u << 16);
        qf[i*8 + 2*j+1] = __uint_as_float(u & 0xFFFF0000u);
      }
    }
  }
  float sv[8]; int si[8];
  #pragma unroll
  for (int j=0;j<8;++j){ sv[j] = -3e38f; si[j] = 0x7fffffff; }
  #pragma unroll
  for (int e=0;e<2;++e){
    int base = ti[2*lg + e];                // this lane rescans 2 of the row's 8 subtiles
    #pragma unroll
    for (int c=0;c<4;++c){
      int col = base + c;
      const unsigned short* krow = kbf + (size_t)col*C_DIM + head*HDIM;
      float s = 0.f;
      #pragma unroll
      for (int i=0;i<4;++i){
        i32x4 kv = *(const i32x4*)(krow + i*8);
        #pragma unroll
        for (int j=0;j<4;++j){
          unsigned u = (unsigned)kv[j];
          s += qf[i*8+2*j]   * __uint_as_float(u << 16);
          s += qf[i*8+2*j+1] * __uint_as_float(u & 0xFFFF0000u);
        }
      }
      // tie-aware sorted insert (8 candidates per lane, unconditional)
      float cv = s; int ci = col;
      #pragma unroll
      for (int j=0;j<8;++j){
        bool gt = (cv > sv[j]) || (cv == sv[j] && ci < si[j]);
        float nv = gt?cv:sv[j]; float ov_ = gt?sv[j]:cv;
        int   ni = gt?ci:si[j]; int   oi_ = gt?si[j]:ci;
        sv[j]=nv; si[j]=ni; cv=ov_; ci=oi_;
      }
    }
  }
  merge_lists(sv, si);   // exact top-8 elements per row

  // ---- phase 3: closed-form masked softmax + PV ----
  __shared__ float lds_e[4][16][8];
  __shared__ int   lds_i[4][16][8];
  __shared__ float lds_d[4][16];
  if (lg == 0){
    float den = 4096.0f;
    #pragma unroll
    for (int j=0;j<8;++j){
      float e = expm1f(sv[j]*SCALE);
      den += e;
      lds_e[wave][l16][j] = e;
      lds_i[wave][l16][j] = si[j];
    }
    lds_d[wave][l16] = den;
  }
  __syncthreads();
  // out[row][head*32+d] = (sumv + sum_j e_j * v[idx_j]) / den
  #pragma unroll
  for (int it=0; it<8; ++it){
    int flat = it*256 + threadIdx.x;      // 64 rows x 32 dims
    int rloc = flat >> 5, d = flat & 31;
    int w2 = rloc >> 4, r2 = rloc & 15;
    float num = sumv[head*HDIM + d];
    float den = lds_d[w2][r2];
    #pragma unroll
    for (int j=0;j<8;++j)
      num += lds_e[w2][r2][j] * v[(size_t)lds_i[w2][r2][j]*C_DIM + head*HDIM + d];
    int rr = blockIdx.x*64 + rloc;
    outbf[(size_t)rr*C_DIM + head*HDIM + d] = f2bf(num/den);
  }
}

// ---------------- LDS-tiled grouped dwconv 3x3 & 5x5 -> cat[p][2048] bf16 ----------------
// block: 8 input channels x 4-row pixel stripe (+-2 halo). 256 threads = 32 o_local x 8 p.
__global__ __launch_bounds__(256) void dwconv_tiled(const float* __restrict__ img, // h2T [256][4096]
    const float* __restrict__ w3, const float* __restrict__ b3,
    const float* __restrict__ w5, const float* __restrict__ b5,
    unsigned short* __restrict__ cat)
{
  __shared__ float tile[8][513];         // 8 channel planes of 8x64, stride 513 (bank spread)
  int ic0 = blockIdx.x * 8;              // input channel group
  int py0 = blockIdx.y * 4;              // pixel row stripe
  int tid = threadIdx.x;

  // stage: 8 ch x 8 rows (py0-2 .. py0+5) x 64, coalesced 256B row segments
  #pragma unroll
  for (int i = 0; i < 16; ++i){
    int idx = i*256 + tid;
    int ch  = idx >> 9;
    int rem = idx & 511;
    int ry  = rem >> 6, x = rem & 63;
    int y   = py0 - 2 + ry;
    float v = (y >= 0 && y < 64) ? img[(size_t)(ic0+ch)*4096 + y*64 + x] : 0.f;
    tile[ch][ry*64 + x] = v;
  }
  __syncthreads();

  int o_l  = tid & 31;                   // 0..31 : ic_l = o_l>>2, multiplier j = o_l&3
  int p_l  = tid >> 5;                   // 0..7
  int ic_l = o_l >> 2;
  int o3   = ic0*4 + o_l;                // output channel index (same for w3/b3 and w5/b5)
  const float* pl = tile[ic_l];

  float W3[9], W5[25];
  #pragma unroll
  for (int i=0;i<9;++i)  W3[i] = w3[o3*9+i];
  #pragma unroll
  for (int i=0;i<25;++i) W5[i] = w5[o3*25+i];
  float bb3 = b3[o3], bb5 = b5[o3];

  #pragma unroll 4
  for (int it = 0; it < 32; ++it){
    int pp = it*8 + p_l;                 // local pixel 0..255
    int ly = (pp >> 6) + 2;              // local row in tile
    int x  = pp & 63;
    float a3 = bb3, a5 = bb5;
    #pragma unroll
    for (int dy=-2; dy<=2; ++dy){
      #pragma unroll
      for (int dx=-2; dx<=2; ++dx){
        int xx = x + dx;
        float iv = (xx >= 0 && xx < 64) ? pl[(ly+dy)*64 + xx] : 0.f;
        a5 += W5[(dy+2)*5 + dx+2] * iv;
        if (dy>=-1 && dy<=1 && dx>=-1 && dx<=1)
          a3 += W3[(dy+1)*3 + dx+1] * iv;
      }
    }
    int p = (py0 + (pp>>6))*64 + x;      // global pixel
    cat[(size_t)p*2048 + o3]        = f2bf(fmaxf(a3, 0.f));
    cat[(size_t)p*2048 + 1024 + o3] = f2bf(fmaxf(a5, 0.f));
  }
}

extern "C" void kernel_launch(void* const* d_in, const int* in_sizes, int n_in,
                              void* d_out, int out_size, void* d_ws, size_t ws_size,
                              hipStream_t stream)
{
  (void)in_sizes; (void)n_in; (void)out_size; (void)ws_size;
  const float* x      = (const float*)d_in[0];
  const float* ln1_g  = (const float*)d_in[3];
  const float* ln1_b  = (const float*)d_in[4];
  const float* q_w    = (const float*)d_in[5];
  const float* q_b    = (const float*)d_in[6];
  const float* kv_w   = (const float*)d_in[7];
  const float* kv_b   = (const float*)d_in[8];
  const float* proj_w = (const float*)d_in[9];
  const float* proj_b = (const float*)d_in[10];
  const float* ln2_g  = (const float*)d_in[11];
  const float* ln2_b  = (const float*)d_in[12];
  const float* w3     = (const float*)d_in[13];
  const float* b3     = (const float*)d_in[14];
  const float* w5     = (const float*)d_in[15];
  const float* b5     = (const float*)d_in[16];
  const float* w1     = (const float*)d_in[17];
  const float* b1     = (const float*)d_in[18];
  float* out = (float*)d_out;
  char* ws = (char*)d_ws;

  unsigned short* qwT  = (unsigned short*)(ws + 0x0);       // 128 KB
  unsigned short* pwT  = (unsigned short*)(ws + 0x20000);   // 128 KB
  unsigned short* kvwT = (unsigned short*)(ws + 0x40000);   // 256 KB
  unsigned short* w1bf = (unsigned short*)(ws + 0x80000);   // 1 MB
  unsigned short* hbf  = (unsigned short*)(ws + 0x180000);  // 2 MB
  unsigned short* qbf  = (unsigned short*)(ws + 0x380000);  // 2 MB
  unsigned short* kbf  = (unsigned short*)(ws + 0x580000);  // 2 MB
  float*          vbuf = (float*)(ws + 0x780000);           // 4 MB
  unsigned short* obf  = (unsigned short*)(ws + 0xB80000);  // 2 MB
  float*          x2   = (float*)(ws + 0xD80000);           // 4 MB
  float*          sumv = (float*)(ws + 0x1180000);          // 1 KB
  float*          part = (float*)(ws + 0x1190000);          // 64 KB
  float*          h2   = (float*)(ws + 0x180000);           // reuse hbf+qbf (dead)
  float*          h2T  = (float*)(ws + 0x580000);           // reuse kbf+v half (dead)
  unsigned short* cat  = (unsigned short*)(ws + 0x1200000); // 16 MB -> end 0x2200000

  dim3 b256(256), b128(128);

  // weight prep
  cvt_bf<<<dim3(2048), b256, 0, stream>>>(w1, w1bf, 256*2048);
  transpose_k<<<dim3(4,4), b256, 0, stream>>>(q_w,   nullptr, qwT,  256, 256);
  transpose_k<<<dim3(8,4), b256, 0, stream>>>(kv_w,  nullptr, kvwT, 256, 512);
  transpose_k<<<dim3(4,4), b256, 0, stream>>>(proj_w,nullptr, pwT,  256, 256);

  // attention branch
  ln_kernel<1><<<dim3(4096), b256, 0, stream>>>(x, ln1_g, ln1_b, nullptr, hbf);
  gemm_mfma<1><<<dim3(128,4), b128, 0, stream>>>(hbf, qwT,           q_b,      nullptr, nullptr, qbf, 256);
  gemm_mfma<0><<<dim3(128,4), b128, 0, stream>>>(hbf, kvwT,          kv_b,     nullptr, nullptr, kbf, 256);
  gemm_mfma<0><<<dim3(128,4), b128, 0, stream>>>(hbf, kvwT + 256*256, kv_b+256, nullptr, vbuf,   nullptr, 256);
  colsum_part <<<dim3(64), b256, 0, stream>>>(vbuf, part);
  colsum_final<<<dim3(1),  b256, 0, stream>>>(part, sumv);
  attn_kernel<<<dim3(64,8), b256, 0, stream>>>(qbf, kbf, vbuf, sumv, obf);
  gemm_mfma<0><<<dim3(128,4), b128, 0, stream>>>(obf, pwT, proj_b, x, x2, nullptr, 256);

  // MSFN branch
  ln_kernel<0><<<dim3(4096), b256, 0, stream>>>(x2, ln2_g, ln2_b, h2, nullptr);
  transpose_k<<<dim3(4,64), b256, 0, stream>>>(h2, h2T, nullptr, 4096, 256);
  dwconv_tiled<<<dim3(32,16), b256, 0, stream>>>(h2T, w3, b3, w5, b5, cat);
  gemm_mfma<0><<<dim3(128,4), b128, 0, stream>>>(cat, w1bf, b1, x2, out, nullptr, 2048);
}